// Round 1
// baseline (887.537 us; speedup 1.0000x reference)
//
#include <hip/hip_runtime.h>

// HOGCN: 2-layer GraphConv, N=50000 nodes, D=64, E=1.6M edges, fp32.
// h = relu(seg_sum(w*x[src]) @ Wrel^T + b + x @ Wroot^T), twice.
// Restructured: Z = x@Wrel^T, Y = x@Wroot^T + b  (node-parallel, W in regs),
// then agg[dst] += w * Z[src] (atomic scatter), epilogue relu(agg + Y).

#define NN 50000
#define DD 64
#define EE 1600000

// One wave per node. Lane j holds W_rel row j and W_root row j in registers
// (128 VGPRs), broadcasts the node's x-row via __shfl.
// FUSED=true: input row = relu(agg[i] + Yin[i])  (layer-2 path; Yin may alias Y:
// each element is read and written by the same thread, so in-place is safe).
template <bool FUSED>
__global__ __launch_bounds__(256) void transform_kernel(
    const float* __restrict__ xin,    // x (layer 1) or agg (layer 2)
    const float* __restrict__ yin,    // Y from previous layer (FUSED only)
    const float* __restrict__ Wrel,   // [64][64] row-major
    const float* __restrict__ Wroot,  // [64][64] row-major
    const float* __restrict__ bias,   // [64]
    float* __restrict__ Z, float* __restrict__ Y)
{
    const int lane  = threadIdx.x & 63;
    const int gwave = blockIdx.x * 4 + (threadIdx.x >> 6);
    const int nwav  = gridDim.x * 4;

    float wrel[DD], wroot[DD];
#pragma unroll
    for (int k = 0; k < DD; k += 4) {
        float4 a = *(const float4*)(Wrel  + lane * DD + k);
        wrel[k] = a.x; wrel[k+1] = a.y; wrel[k+2] = a.z; wrel[k+3] = a.w;
        float4 b = *(const float4*)(Wroot + lane * DD + k);
        wroot[k] = b.x; wroot[k+1] = b.y; wroot[k+2] = b.z; wroot[k+3] = b.w;
    }
    const float bj = bias[lane];

    for (int i = gwave; i < NN; i += nwav) {
        float xv;
        if (FUSED) {
            xv = fmaxf(xin[i * DD + lane] + yin[i * DD + lane], 0.0f);
        } else {
            xv = xin[i * DD + lane];
        }
        float ar = 0.0f, ao = 0.0f;
#pragma unroll
        for (int k = 0; k < DD; ++k) {
            float xk = __shfl(xv, k);
            ar = fmaf(xk, wrel[k],  ar);
            ao = fmaf(xk, wroot[k], ao);
        }
        Z[i * DD + lane] = ar;
        Y[i * DD + lane] = ao + bj;
    }
}

// One thread per (edge, feature). Consecutive 64 threads = one edge, so the
// Z-row gather and the atomic adds are both 256B-coalesced per wave.
__global__ __launch_bounds__(256) void scatter_kernel(
    const float* __restrict__ Z,
    const int* __restrict__ ei,       // [2][E]: src row then dst row
    const float* __restrict__ ew,     // [E]
    float* __restrict__ agg)
{
    unsigned g = blockIdx.x * 256u + threadIdx.x;
    int e = g >> 6;
    int d = g & 63;
    int src = ei[e];
    int dst = ei[EE + e];
    float w  = ew[e];
    atomicAdd(agg + dst * DD + d, w * Z[src * DD + d]);
}

__global__ __launch_bounds__(256) void epilogue_kernel(
    float* __restrict__ out, const float* __restrict__ Y)
{
    int g = blockIdx.x * 256 + threadIdx.x;   // over N*D/4 float4 elements
    float4 a = ((const float4*)out)[g];
    float4 y = ((const float4*)Y)[g];
    a.x = fmaxf(a.x + y.x, 0.0f);
    a.y = fmaxf(a.y + y.y, 0.0f);
    a.z = fmaxf(a.z + y.z, 0.0f);
    a.w = fmaxf(a.w + y.w, 0.0f);
    ((float4*)out)[g] = a;
}

extern "C" void kernel_launch(void* const* d_in, const int* in_sizes, int n_in,
                              void* d_out, int out_size, void* d_ws, size_t ws_size,
                              hipStream_t stream)
{
    const float* x     = (const float*)d_in[0];
    const int*   ei    = (const int*)  d_in[1];
    const float* ew    = (const float*)d_in[2];
    const float* Wrel1 = (const float*)d_in[3];
    const float* brel1 = (const float*)d_in[4];
    const float* Wroot1= (const float*)d_in[5];
    const float* Wrel2 = (const float*)d_in[6];
    const float* brel2 = (const float*)d_in[7];
    const float* Wroot2= (const float*)d_in[8];

    float* out = (float*)d_out;          // also serves as the agg accumulator
    float* Z   = (float*)d_ws;           // [N][D]
    float* Y   = Z + (size_t)NN * DD;    // [N][D]

    const size_t nd_bytes = (size_t)NN * DD * sizeof(float);
    const int scatter_blocks = (EE * DD) / 256;   // 400000
    const int ep_blocks      = (NN * DD / 4) / 256; // 3125

    // ---- layer 1 ----
    transform_kernel<false><<<1024, 256, 0, stream>>>(x, nullptr, Wrel1, Wroot1, brel1, Z, Y);
    hipMemsetAsync(out, 0, nd_bytes, stream);
    scatter_kernel<<<scatter_blocks, 256, 0, stream>>>(Z, ei, ew, out);

    // ---- layer 2 (fuses layer-1 relu epilogue into the transform) ----
    transform_kernel<true><<<1024, 256, 0, stream>>>(out, Y, Wrel2, Wroot2, brel2, Z, Y);
    hipMemsetAsync(out, 0, nd_bytes, stream);
    scatter_kernel<<<scatter_blocks, 256, 0, stream>>>(Z, ei, ew, out);

    epilogue_kernel<<<ep_blocks, 256, 0, stream>>>(out, Y);
}

// Round 2
// 648.862 us; speedup vs baseline: 1.3678x; 1.3678x over previous
//
#include <hip/hip_runtime.h>

// HOGCN: 2-layer GraphConv, N=50000, D=64, E=1.6M, fp32.
// Round 2: replace per-(edge,feature) fp32 atomics (atomic-pipe bound,
// 298G atomics/s = ~124/clk chip-wide ceiling, 400MB write traffic) with a
// counting-sort CSR build (once, shared by both layers) + per-dst-node
// register aggregation. Epilogue relu(agg+Y) fused into aggregation.

#define NN 50000
#define DD 64
#define EE 1600000

// ---------- CSR build ----------

__global__ __launch_bounds__(256) void hist_kernel(
    const int* __restrict__ ei, int* __restrict__ counts)
{
    int e = blockIdx.x * 256 + threadIdx.x;
    if (e >= EE) return;
    atomicAdd(&counts[ei[EE + e]], 1);   // dst row
}

// Single-block exclusive scan over counts[0..NN) -> offsets[0..NN], cursor copy.
__global__ __launch_bounds__(1024) void scan_kernel(
    const int* __restrict__ counts, int* __restrict__ offsets,
    int* __restrict__ cursor)
{
    __shared__ int part[1024];
    const int t = threadIdx.x;
    const int chunk = (NN + 1023) / 1024;          // 49
    const int begin = t * chunk;
    const int end   = min(begin + chunk, NN);
    int s = 0;
    for (int i = begin; i < end; ++i) s += counts[i];
    part[t] = s;
    __syncthreads();
    // Hillis-Steele inclusive scan over 1024 partials
    for (int off = 1; off < 1024; off <<= 1) {
        int v = (t >= off) ? part[t - off] : 0;
        __syncthreads();
        part[t] += v;
        __syncthreads();
    }
    int prefix = (t == 0) ? 0 : part[t - 1];
    for (int i = begin; i < end; ++i) {
        offsets[i] = prefix;
        cursor[i]  = prefix;
        prefix += counts[i];
    }
    if (t == 1023) offsets[NN] = EE;
}

// Scatter each edge's (src, weight) into its dst bucket.
__global__ __launch_bounds__(256) void fill_kernel(
    const int* __restrict__ ei, const float* __restrict__ ew,
    int* __restrict__ cursor, int2* __restrict__ packed)
{
    int e = blockIdx.x * 256 + threadIdx.x;
    if (e >= EE) return;
    int src = ei[e];
    int dst = ei[EE + e];
    int pos = atomicAdd(&cursor[dst], 1);
    packed[pos] = make_int2(src, __float_as_int(ew[e]));
}

// ---------- dense transforms ----------
// One wave per node; lane j holds W_rel/W_root row j in registers,
// broadcasts the node's x-row via __shfl. Z = x@Wrel^T, Y = x@Wroot^T + b.
__global__ __launch_bounds__(256) void transform_kernel(
    const float* __restrict__ xin,
    const float* __restrict__ Wrel, const float* __restrict__ Wroot,
    const float* __restrict__ bias,
    float* __restrict__ Z, float* __restrict__ Y)
{
    const int lane  = threadIdx.x & 63;
    const int gwave = blockIdx.x * 4 + (threadIdx.x >> 6);
    const int nwav  = gridDim.x * 4;

    float wrel[DD], wroot[DD];
#pragma unroll
    for (int k = 0; k < DD; k += 4) {
        float4 a = *(const float4*)(Wrel  + lane * DD + k);
        wrel[k] = a.x; wrel[k+1] = a.y; wrel[k+2] = a.z; wrel[k+3] = a.w;
        float4 b = *(const float4*)(Wroot + lane * DD + k);
        wroot[k] = b.x; wroot[k+1] = b.y; wroot[k+2] = b.z; wroot[k+3] = b.w;
    }
    const float bj = bias[lane];

    for (int i = gwave; i < NN; i += nwav) {
        float xv = xin[i * DD + lane];
        float ar = 0.0f, ao = 0.0f;
#pragma unroll
        for (int k = 0; k < DD; ++k) {
            float xk = __shfl(xv, k);
            ar = fmaf(xk, wrel[k],  ar);
            ao = fmaf(xk, wroot[k], ao);
        }
        Z[i * DD + lane] = ar;
        Y[i * DD + lane] = ao + bj;
    }
}

// ---------- aggregation (fused epilogue) ----------
// One wave per dst node, lane = feature. H[i] = relu(sum_e w_e*Z[src_e] + Y[i]).
__global__ __launch_bounds__(256) void aggregate_kernel(
    const float* __restrict__ Z, const float* __restrict__ Y,
    const int* __restrict__ offsets, const int2* __restrict__ packed,
    float* __restrict__ H)
{
    const int lane = threadIdx.x & 63;
    const int node = blockIdx.x * 4 + (threadIdx.x >> 6);
    if (node >= NN) return;

    const int b = offsets[node];
    const int e = offsets[node + 1];
    float acc = 0.0f;
    int i = b;
    for (; i + 1 < e; i += 2) {          // 2-way unroll for load ILP
        int2 p0 = packed[i];
        int2 p1 = packed[i + 1];
        float z0 = Z[p0.x * DD + lane];
        float z1 = Z[p1.x * DD + lane];
        acc = fmaf(__int_as_float(p0.y), z0, acc);
        acc = fmaf(__int_as_float(p1.y), z1, acc);
    }
    if (i < e) {
        int2 p = packed[i];
        acc = fmaf(__int_as_float(p.y), Z[p.x * DD + lane], acc);
    }
    H[node * DD + lane] = fmaxf(acc + Y[node * DD + lane], 0.0f);
}

extern "C" void kernel_launch(void* const* d_in, const int* in_sizes, int n_in,
                              void* d_out, int out_size, void* d_ws, size_t ws_size,
                              hipStream_t stream)
{
    const float* x     = (const float*)d_in[0];
    const int*   ei    = (const int*)  d_in[1];
    const float* ew    = (const float*)d_in[2];
    const float* Wrel1 = (const float*)d_in[3];
    const float* brel1 = (const float*)d_in[4];
    const float* Wroot1= (const float*)d_in[5];
    const float* Wrel2 = (const float*)d_in[6];
    const float* brel2 = (const float*)d_in[7];
    const float* Wroot2= (const float*)d_in[8];

    float* out = (float*)d_out;                 // H1 (layer-1 output) and final

    // workspace layout (floats)
    float* Z       = (float*)d_ws;              // [N*D]
    float* Y       = Z + (size_t)NN * DD;       // [N*D]
    int2*  packed  = (int2*)(Y + (size_t)NN * DD);   // [E] (src, weight-bits)
    int*   counts  = (int*)(packed + EE);       // [N]
    int*   offsets = counts + NN;               // [N+1]
    int*   cursor  = offsets + NN + 1;          // [N]

    const int eb  = (EE + 255) / 256;           // 6250
    const int nb4 = (NN + 3) / 4;               // 12500 (4 waves/block)

    // ---- CSR build (graph identical for both layers) ----
    hipMemsetAsync(counts, 0, NN * sizeof(int), stream);
    hist_kernel<<<eb, 256, 0, stream>>>(ei, counts);
    scan_kernel<<<1, 1024, 0, stream>>>(counts, offsets, cursor);
    fill_kernel<<<eb, 256, 0, stream>>>(ei, ew, cursor, packed);

    // ---- layer 1 ----
    transform_kernel<<<1024, 256, 0, stream>>>(x, Wrel1, Wroot1, brel1, Z, Y);
    aggregate_kernel<<<nb4, 256, 0, stream>>>(Z, Y, offsets, packed, out);

    // ---- layer 2 ----
    transform_kernel<<<1024, 256, 0, stream>>>(out, Wrel2, Wroot2, brel2, Z, Y);
    aggregate_kernel<<<nb4, 256, 0, stream>>>(Z, Y, offsets, packed, out);
}